// Round 1
// baseline (594.000 us; speedup 1.0000x reference)
//
#include <hip/hip_runtime.h>

typedef __bf16 bf16x8 __attribute__((ext_vector_type(8)));
typedef float f32x4 __attribute__((ext_vector_type(4)));

constexpr int B = 4, S = 4096, D = 256;
// log2(e) / sqrt(D) = 1.4426950408889634 / 16
constexpr float CSC = 0.09016844005556021f;

static __device__ __forceinline__ unsigned short f2bf(float f) {
  unsigned int u = __builtin_bit_cast(unsigned int, f);
  u = (u + 0x7fffu + ((u >> 16) & 1u)) >> 16;
  return (unsigned short)u;
}

// ---- kernel 1: cast x -> bf16, and build xT[b][d][s] (bf16) ----
__global__ __launch_bounds__(256) void k_prep(const float* __restrict__ x,
                                              unsigned short* __restrict__ xbf,
                                              unsigned short* __restrict__ xT) {
  __shared__ unsigned short T[64][65];
  int bid = blockIdx.x;
  int b = bid >> 8, rem = bid & 255;
  int s0 = (rem >> 2) * 64, d0 = (rem & 3) * 64;
  int j = threadIdx.x & 63, i0 = threadIdx.x >> 6;
#pragma unroll
  for (int k = 0; k < 16; ++k) {
    int i = k * 4 + i0;
    int idx = (b * S + s0 + i) * D + d0 + j;
    unsigned short v = f2bf(x[idx]);
    xbf[idx] = v;
    T[j][i] = v;  // T[d_local][s_local]
  }
  __syncthreads();
#pragma unroll
  for (int k = 0; k < 16; ++k) {
    int i = k * 4 + i0;  // d_local row
    xT[(b * D + d0 + i) * S + s0 + j] = T[i][j];
  }
}

// ---- kernel 2: w_int -> bf16 (integers < 256 are exact in bf16) ----
__global__ __launch_bounds__(256) void k_deqw(const int* __restrict__ w,
                                              unsigned short* __restrict__ wbf) {
  int i = blockIdx.x * 256 + threadIdx.x;
  wbf[i] = f2bf((float)w[i]);
}

// ---- kernel 3: flash attention (bf16 MFMA, f32 softmax) ----
// 1 wave per block, 16 q-rows per wave, KV step 64.
__global__ __launch_bounds__(64) void k_attn(const unsigned short* __restrict__ xbf,
                                             const unsigned short* __restrict__ xT,
                                             unsigned short* __restrict__ attn) {
  __shared__ float P[16 * 68];  // stride 68 f32: rows r, r+8 share banks (2-way = free)
  int lane = threadIdx.x;
  int g = lane >> 4, c = lane & 15;

  int bid = blockIdx.x;
  int swz = (bid & 7) * 128 + (bid >> 3);  // bijective XCD swizzle (1024 % 8 == 0)
  int b = swz >> 8;
  int q0 = (swz & 255) * 16;

  const unsigned short* Xb = xbf + b * (S * D);
  const unsigned short* XTb = xT + b * (D * S);

  // Q fragments: lane holds Q[q0+c][dk*32 + 8g .. +8]
  bf16x8 qf[8];
#pragma unroll
  for (int dk = 0; dk < 8; ++dk)
    qf[dk] = *(const bf16x8*)(Xb + (q0 + c) * D + dk * 32 + g * 8);

  const f32x4 zero = {0.f, 0.f, 0.f, 0.f};
  f32x4 acc[16];
#pragma unroll
  for (int i = 0; i < 16; ++i) acc[i] = zero;
  float m_r[4] = {-1e30f, -1e30f, -1e30f, -1e30f};
  float l_r[4] = {0.f, 0.f, 0.f, 0.f};

  for (int kv0 = 0; kv0 < S; kv0 += 64) {
    // ---- scores: S[q][kv] = sum_d Q[q][d] * K[kv][d]  (4 tiles of 16 kv)
    f32x4 st[4];
#pragma unroll
    for (int t = 0; t < 4; ++t) {
      st[t] = zero;
      const unsigned short* Kr = Xb + (kv0 + t * 16 + c) * D + g * 8;
#pragma unroll
      for (int dk = 0; dk < 8; ++dk) {
        bf16x8 kf = *(const bf16x8*)(Kr + dk * 32);
        st[t] = __builtin_amdgcn_mfma_f32_16x16x32_bf16(qf[dk], kf, st[t], 0, 0, 0);
      }
    }
    // st[t][r] = S_raw[q0+4g+r][kv0+16t+c]

    // ---- online softmax (f32). row max over kv: local over t, then 16-lane butterfly
    float tm[4];
#pragma unroll
    for (int r = 0; r < 4; ++r)
      tm[r] = fmaxf(fmaxf(st[0][r], st[1][r]), fmaxf(st[2][r], st[3][r]));
#pragma unroll
    for (int off = 1; off < 16; off <<= 1) {
#pragma unroll
      for (int r = 0; r < 4; ++r) tm[r] = fmaxf(tm[r], __shfl_xor(tm[r], off, 64));
    }
    float corr[4];
#pragma unroll
    for (int r = 0; r < 4; ++r) {
      float mn = fmaxf(m_r[r], tm[r]);
      corr[r] = exp2f((m_r[r] - mn) * CSC);
      m_r[r] = mn;
    }
    float ps[4][4];
    float tsum[4] = {0.f, 0.f, 0.f, 0.f};
#pragma unroll
    for (int t = 0; t < 4; ++t) {
#pragma unroll
      for (int r = 0; r < 4; ++r) {
        float p = exp2f((st[t][r] - m_r[r]) * CSC);
        ps[t][r] = p;
        tsum[r] += p;
      }
    }
#pragma unroll
    for (int off = 1; off < 16; off <<= 1) {
#pragma unroll
      for (int r = 0; r < 4; ++r) tsum[r] += __shfl_xor(tsum[r], off, 64);
    }
#pragma unroll
    for (int r = 0; r < 4; ++r) l_r[r] = l_r[r] * corr[r] + tsum[r];
#pragma unroll
    for (int i = 0; i < 16; ++i) {
#pragma unroll
      for (int r = 0; r < 4; ++r) acc[i][r] *= corr[r];
    }

    // ---- transpose P through LDS: write S-layout, read A-fragment layout
#pragma unroll
    for (int t = 0; t < 4; ++t) {
#pragma unroll
      for (int r = 0; r < 4; ++r) P[(4 * g + r) * 68 + t * 16 + c] = ps[t][r];
    }

    // ---- PV: O[q][d] += P[q][kv] * V[kv][d], B-operand from xT (contiguous)
#pragma unroll
    for (int h = 0; h < 2; ++h) {
      f32x4 p0 = *(const f32x4*)&P[c * 68 + h * 32 + g * 8];
      f32x4 p1 = *(const f32x4*)&P[c * 68 + h * 32 + g * 8 + 4];
      bf16x8 pa;
#pragma unroll
      for (int jj = 0; jj < 4; ++jj) {
        pa[jj] = (__bf16)p0[jj];
        pa[jj + 4] = (__bf16)p1[jj];
      }
#pragma unroll
      for (int dc = 0; dc < 16; ++dc) {
        bf16x8 vf = *(const bf16x8*)(XTb + (dc * 16 + c) * S + kv0 + h * 32 + g * 8);
        acc[dc] = __builtin_amdgcn_mfma_f32_16x16x32_bf16(pa, vf, acc[dc], 0, 0, 0);
      }
    }
  }

  // ---- epilogue: O /= l, store bf16
  float il[4];
#pragma unroll
  for (int r = 0; r < 4; ++r) il[r] = 1.f / l_r[r];
  unsigned short* Ab = attn + b * (S * D);
#pragma unroll
  for (int dc = 0; dc < 16; ++dc) {
#pragma unroll
    for (int r = 0; r < 4; ++r)
      Ab[(q0 + 4 * g + r) * D + dc * 16 + c] = f2bf(acc[dc][r] * il[r]);
  }
}

// ---- kernel 4: out[m][o] = scale[o] * sum_d attn[m][d] * Wint[o][d] ----
__global__ __launch_bounds__(64) void k_gemm(const unsigned short* __restrict__ attn,
                                             const unsigned short* __restrict__ wbf,
                                             const float* __restrict__ scale,
                                             float* __restrict__ out) {
  int lane = threadIdx.x, g = lane >> 4, c = lane & 15;
  int m0 = blockIdx.x * 16;
  bf16x8 af[8];
#pragma unroll
  for (int dk = 0; dk < 8; ++dk)
    af[dk] = *(const bf16x8*)(attn + (m0 + c) * D + dk * 32 + g * 8);
  const f32x4 zero = {0.f, 0.f, 0.f, 0.f};
  f32x4 acc[16];
#pragma unroll
  for (int i = 0; i < 16; ++i) acc[i] = zero;
#pragma unroll
  for (int oc = 0; oc < 16; ++oc) {
#pragma unroll
    for (int dk = 0; dk < 8; ++dk) {
      bf16x8 wf = *(const bf16x8*)(wbf + (oc * 16 + c) * D + dk * 32 + g * 8);
      acc[oc] = __builtin_amdgcn_mfma_f32_16x16x32_bf16(af[dk], wf, acc[oc], 0, 0, 0);
    }
  }
#pragma unroll
  for (int oc = 0; oc < 16; ++oc) {
    float sc = scale[oc * 16 + c];
#pragma unroll
    for (int r = 0; r < 4; ++r)
      out[(m0 + 4 * g + r) * D + oc * 16 + c] = acc[oc][r] * sc;
  }
}

extern "C" void kernel_launch(void* const* d_in, const int* in_sizes, int n_in,
                              void* d_out, int out_size, void* d_ws, size_t ws_size,
                              hipStream_t stream) {
  (void)in_sizes; (void)n_in; (void)out_size; (void)ws_size;
  const float* x = (const float*)d_in[0];
  const int* w_int = (const int*)d_in[1];
  const float* scale = (const float*)d_in[2];
  float* out = (float*)d_out;

  char* ws = (char*)d_ws;
  unsigned short* xbf  = (unsigned short*)(ws);
  unsigned short* xT   = (unsigned short*)(ws + 8388608);
  unsigned short* attn = (unsigned short*)(ws + 16777216);
  unsigned short* wbf  = (unsigned short*)(ws + 25165824);

  k_prep<<<dim3(1024), dim3(256), 0, stream>>>(x, xbf, xT);
  k_deqw<<<dim3(256), dim3(256), 0, stream>>>(w_int, wbf);
  k_attn<<<dim3(1024), dim3(64), 0, stream>>>(xbf, xT, attn);
  k_gemm<<<dim3(1024), dim3(64), 0, stream>>>(attn, wbf, scale, out);
}

// Round 2
// 590.903 us; speedup vs baseline: 1.0052x; 1.0052x over previous
//
#include <hip/hip_runtime.h>

typedef __bf16 bf16x8 __attribute__((ext_vector_type(8)));
typedef float f32x4 __attribute__((ext_vector_type(4)));

constexpr int B = 4, S = 4096, D = 256;
// log2(e) / sqrt(D) = 1.4426950408889634 / 16
constexpr float CSC = 0.09016844005556021f;

static __device__ __forceinline__ unsigned short f2bf(float f) {
  unsigned int u = __builtin_bit_cast(unsigned int, f);
  u = (u + 0x7fffu + ((u >> 16) & 1u)) >> 16;
  return (unsigned short)u;
}

// ---- kernel 1: cast x -> bf16, and build xT[b][d][s] (bf16) ----
__global__ __launch_bounds__(256) void k_prep(const float* __restrict__ x,
                                              unsigned short* __restrict__ xbf,
                                              unsigned short* __restrict__ xT) {
  __shared__ unsigned short T[64][65];
  int bid = blockIdx.x;
  int b = bid >> 8, rem = bid & 255;
  int s0 = (rem >> 2) * 64, d0 = (rem & 3) * 64;
  int j = threadIdx.x & 63, i0 = threadIdx.x >> 6;
#pragma unroll
  for (int k = 0; k < 16; ++k) {
    int i = k * 4 + i0;
    int idx = (b * S + s0 + i) * D + d0 + j;
    unsigned short v = f2bf(x[idx]);
    xbf[idx] = v;
    T[j][i] = v;  // T[d_local][s_local]
  }
  __syncthreads();
#pragma unroll
  for (int k = 0; k < 16; ++k) {
    int i = k * 4 + i0;  // d_local row
    xT[(b * D + d0 + i) * S + s0 + j] = T[i][j];
  }
}

// ---- kernel 2: w_int -> bf16 (integers < 256 are exact in bf16) ----
__global__ __launch_bounds__(256) void k_deqw(const int* __restrict__ w,
                                              unsigned short* __restrict__ wbf) {
  int i = blockIdx.x * 256 + threadIdx.x;
  wbf[i] = f2bf((float)w[i]);
}

// ---- kernel 3: flash attention, split-KV x4 ----
// Block = 4 waves, all on the SAME 16 q-rows; wave w covers kv tiles
// {w, w+4, w+8, ...} (stride 256 rows). Online-softmax partials merged in LDS.
__global__ __launch_bounds__(256, 4) void k_attn(const unsigned short* __restrict__ xbf,
                                                 const unsigned short* __restrict__ xT,
                                                 unsigned short* __restrict__ attn) {
  __shared__ float P[4][16 * 68];   // per-wave P transpose (stride 68: 2-way = free)
  __shared__ float CB[4][16 * 64];  // combine chunk buffer
  __shared__ float ML[2][4][16];    // [m|l][wave][row]
  __shared__ float ILF[16];         // 1/l_final per row

  int tid = threadIdx.x;
  int w = tid >> 6, lane = tid & 63;
  int g = lane >> 4, c = lane & 15;

  int bid = blockIdx.x;
  int swz = (bid & 7) * 128 + (bid >> 3);  // bijective XCD swizzle (1024 % 8 == 0)
  int b = swz >> 8;
  int q0 = (swz & 255) * 16;

  const unsigned short* Xb = xbf + b * (S * D);
  const unsigned short* XTb = xT + b * (D * S);

  // Q fragments: lane holds Q[q0+c][dk*32 + 8g .. +8]
  bf16x8 qf[8];
#pragma unroll
  for (int dk = 0; dk < 8; ++dk)
    qf[dk] = *(const bf16x8*)(Xb + (q0 + c) * D + dk * 32 + g * 8);

  const f32x4 zero = {0.f, 0.f, 0.f, 0.f};
  f32x4 acc[16];
#pragma unroll
  for (int i = 0; i < 16; ++i) acc[i] = zero;
  float m_r[4] = {-1e30f, -1e30f, -1e30f, -1e30f};
  float l_r[4] = {0.f, 0.f, 0.f, 0.f};

  float* Pw = P[w];

  for (int j = 0; j < 16; ++j) {
    int kv0 = j * 256 + w * 64;
    // ---- scores: S[q][kv] = sum_d Q[q][d] * K[kv][d]  (4 tiles of 16 kv)
    f32x4 st[4];
#pragma unroll
    for (int t = 0; t < 4; ++t) {
      st[t] = zero;
      const unsigned short* Kr = Xb + (kv0 + t * 16 + c) * D + g * 8;
#pragma unroll
      for (int dk = 0; dk < 8; ++dk) {
        bf16x8 kf = *(const bf16x8*)(Kr + dk * 32);
        st[t] = __builtin_amdgcn_mfma_f32_16x16x32_bf16(qf[dk], kf, st[t], 0, 0, 0);
      }
    }
    // st[t][r] = S_raw[q0+4g+r][kv0+16t+c]

    // ---- online softmax (f32)
    float tm[4];
#pragma unroll
    for (int r = 0; r < 4; ++r)
      tm[r] = fmaxf(fmaxf(st[0][r], st[1][r]), fmaxf(st[2][r], st[3][r]));
#pragma unroll
    for (int off = 1; off < 16; off <<= 1) {
#pragma unroll
      for (int r = 0; r < 4; ++r) tm[r] = fmaxf(tm[r], __shfl_xor(tm[r], off, 64));
    }
    float corr[4];
#pragma unroll
    for (int r = 0; r < 4; ++r) {
      float mn = fmaxf(m_r[r], tm[r]);
      corr[r] = exp2f((m_r[r] - mn) * CSC);
      m_r[r] = mn;
    }
    float ps[4][4];
    float tsum[4] = {0.f, 0.f, 0.f, 0.f};
#pragma unroll
    for (int t = 0; t < 4; ++t) {
#pragma unroll
      for (int r = 0; r < 4; ++r) {
        float p = exp2f((st[t][r] - m_r[r]) * CSC);
        ps[t][r] = p;
        tsum[r] += p;
      }
    }
#pragma unroll
    for (int off = 1; off < 16; off <<= 1) {
#pragma unroll
      for (int r = 0; r < 4; ++r) tsum[r] += __shfl_xor(tsum[r], off, 64);
    }
#pragma unroll
    for (int r = 0; r < 4; ++r) l_r[r] = l_r[r] * corr[r] + tsum[r];
#pragma unroll
    for (int i = 0; i < 16; ++i) {
#pragma unroll
      for (int r = 0; r < 4; ++r) acc[i][r] *= corr[r];
    }

    // ---- transpose P through per-wave LDS
#pragma unroll
    for (int t = 0; t < 4; ++t) {
#pragma unroll
      for (int r = 0; r < 4; ++r) Pw[(4 * g + r) * 68 + t * 16 + c] = ps[t][r];
    }

    // ---- PV: O[q][d] += P[q][kv] * V[kv][d]
#pragma unroll
    for (int h = 0; h < 2; ++h) {
      f32x4 p0 = *(const f32x4*)&Pw[c * 68 + h * 32 + g * 8];
      f32x4 p1 = *(const f32x4*)&Pw[c * 68 + h * 32 + g * 8 + 4];
      bf16x8 pa;
#pragma unroll
      for (int jj = 0; jj < 4; ++jj) {
        pa[jj] = (__bf16)p0[jj];
        pa[jj + 4] = (__bf16)p1[jj];
      }
#pragma unroll
      for (int dc = 0; dc < 16; ++dc) {
        bf16x8 vf = *(const bf16x8*)(XTb + (dc * 16 + c) * S + kv0 + h * 32 + g * 8);
        acc[dc] = __builtin_amdgcn_mfma_f32_16x16x32_bf16(pa, vf, acc[dc], 0, 0, 0);
      }
    }
  }

  // ---- epilogue: merge 4 wave partials, divide by l, store bf16
  if (c == 0) {
#pragma unroll
    for (int r = 0; r < 4; ++r) {
      ML[0][w][4 * g + r] = m_r[r];
      ML[1][w][4 * g + r] = l_r[r];
    }
  }
  __syncthreads();

  if (tid < 16) {
    float m0 = ML[0][0][tid], m1 = ML[0][1][tid], m2 = ML[0][2][tid], m3 = ML[0][3][tid];
    float ms = fmaxf(fmaxf(m0, m1), fmaxf(m2, m3));
    float lf = ML[1][0][tid] * exp2f((m0 - ms) * CSC) + ML[1][1][tid] * exp2f((m1 - ms) * CSC) +
               ML[1][2][tid] * exp2f((m2 - ms) * CSC) + ML[1][3][tid] * exp2f((m3 - ms) * CSC);
    ILF[tid] = 1.f / lf;
  }

  float fac[4];
#pragma unroll
  for (int r = 0; r < 4; ++r) {
    int row = 4 * g + r;
    float ms = fmaxf(fmaxf(ML[0][0][row], ML[0][1][row]), fmaxf(ML[0][2][row], ML[0][3][row]));
    fac[r] = exp2f((m_r[r] - ms) * CSC);
  }

  unsigned short* Ab = attn + b * (S * D);
#pragma unroll
  for (int chunk = 0; chunk < 4; ++chunk) {
#pragma unroll
    for (int cc = 0; cc < 4; ++cc) {
      int dc = chunk * 4 + cc;
#pragma unroll
      for (int r = 0; r < 4; ++r) CB[w][(4 * g + r) * 64 + cc * 16 + c] = acc[dc][r] * fac[r];
    }
    __syncthreads();
#pragma unroll
    for (int i = 0; i < 4; ++i) {
      int pos = i * 256 + tid;
      int row = pos >> 6, col = pos & 63;
      float v = CB[0][pos] + CB[1][pos] + CB[2][pos] + CB[3][pos];
      Ab[(q0 + row) * D + chunk * 64 + col] = f2bf(v * ILF[row]);
    }
    __syncthreads();
  }
}

// ---- kernel 4: out[m][o] = scale[o] * sum_d attn[m][d] * Wint[o][d] ----
// grid (1024 m-tiles, 4 o-chunks of 64) -> 4096 waves = 4/SIMD
__global__ __launch_bounds__(64) void k_gemm(const unsigned short* __restrict__ attn,
                                             const unsigned short* __restrict__ wbf,
                                             const float* __restrict__ scale,
                                             float* __restrict__ out) {
  int lane = threadIdx.x, g = lane >> 4, c = lane & 15;
  int m0 = blockIdx.x * 16;
  int o0 = blockIdx.y * 64;
  bf16x8 af[8];
#pragma unroll
  for (int dk = 0; dk < 8; ++dk)
    af[dk] = *(const bf16x8*)(attn + (m0 + c) * D + dk * 32 + g * 8);
  const f32x4 zero = {0.f, 0.f, 0.f, 0.f};
  f32x4 acc[4];
#pragma unroll
  for (int i = 0; i < 4; ++i) acc[i] = zero;
#pragma unroll
  for (int oc = 0; oc < 4; ++oc) {
#pragma unroll
    for (int dk = 0; dk < 8; ++dk) {
      bf16x8 wf = *(const bf16x8*)(wbf + (o0 + oc * 16 + c) * D + dk * 32 + g * 8);
      acc[oc] = __builtin_amdgcn_mfma_f32_16x16x32_bf16(af[dk], wf, acc[oc], 0, 0, 0);
    }
  }
#pragma unroll
  for (int oc = 0; oc < 4; ++oc) {
    float sc = scale[o0 + oc * 16 + c];
#pragma unroll
    for (int r = 0; r < 4; ++r)
      out[(m0 + 4 * g + r) * D + o0 + oc * 16 + c] = acc[oc][r] * sc;
  }
}

extern "C" void kernel_launch(void* const* d_in, const int* in_sizes, int n_in,
                              void* d_out, int out_size, void* d_ws, size_t ws_size,
                              hipStream_t stream) {
  (void)in_sizes; (void)n_in; (void)out_size; (void)ws_size;
  const float* x = (const float*)d_in[0];
  const int* w_int = (const int*)d_in[1];
  const float* scale = (const float*)d_in[2];
  float* out = (float*)d_out;

  char* ws = (char*)d_ws;
  unsigned short* xbf  = (unsigned short*)(ws);
  unsigned short* xT   = (unsigned short*)(ws + 8388608);
  unsigned short* attn = (unsigned short*)(ws + 16777216);
  unsigned short* wbf  = (unsigned short*)(ws + 25165824);

  k_prep<<<dim3(1024), dim3(256), 0, stream>>>(x, xbf, xT);
  k_deqw<<<dim3(256), dim3(256), 0, stream>>>(w_int, wbf);
  k_attn<<<dim3(1024), dim3(256), 0, stream>>>(xbf, xT, attn);
  k_gemm<<<dim3(1024, 4), dim3(64), 0, stream>>>(attn, wbf, scale, out);
}

// Round 3
// 580.839 us; speedup vs baseline: 1.0227x; 1.0173x over previous
//
#include <hip/hip_runtime.h>

typedef __bf16 bf16x8 __attribute__((ext_vector_type(8)));
typedef float f32x4 __attribute__((ext_vector_type(4)));

constexpr int B = 4, S = 4096, D = 256;
// log2(e) / sqrt(D) = 1.4426950408889634 / 16
constexpr float CSC = 0.09016844005556021f;

static __device__ __forceinline__ unsigned short f2bf(float f) {
  unsigned int u = __builtin_bit_cast(unsigned int, f);
  u = (u + 0x7fffu + ((u >> 16) & 1u)) >> 16;
  return (unsigned short)u;
}

// ---- kernel 1: cast x -> bf16, and build xT[b][d][s] (bf16) ----
__global__ __launch_bounds__(256) void k_prep(const float* __restrict__ x,
                                              unsigned short* __restrict__ xbf,
                                              unsigned short* __restrict__ xT) {
  __shared__ unsigned short T[64][65];
  int bid = blockIdx.x;
  int b = bid >> 8, rem = bid & 255;
  int s0 = (rem >> 2) * 64, d0 = (rem & 3) * 64;
  int j = threadIdx.x & 63, i0 = threadIdx.x >> 6;
#pragma unroll
  for (int k = 0; k < 16; ++k) {
    int i = k * 4 + i0;
    int idx = (b * S + s0 + i) * D + d0 + j;
    unsigned short v = f2bf(x[idx]);
    xbf[idx] = v;
    T[j][i] = v;  // T[d_local][s_local]
  }
  __syncthreads();
#pragma unroll
  for (int k = 0; k < 16; ++k) {
    int i = k * 4 + i0;  // d_local row
    xT[(b * D + d0 + i) * S + s0 + j] = T[i][j];
  }
}

// ---- kernel 2: w_int -> bf16 (integers < 256 are exact in bf16) ----
__global__ __launch_bounds__(256) void k_deqw(const int* __restrict__ w,
                                              unsigned short* __restrict__ wbf) {
  int i = blockIdx.x * 256 + threadIdx.x;
  wbf[i] = f2bf((float)w[i]);
}

// ---- kernel 3: flash attention, split-KV x4 ----
// Block = 4 waves, all on the SAME 16 q-rows; wave w covers kv tiles
// {w, w+4, w+8, ...} (stride 256 rows). Online-softmax partials merged in LDS.
// launch_bounds(256,2): VGPR cap 256 -> NO spills (R2's (256,4) cap of 128
// caused 800 MB of scratch traffic).
__global__ __launch_bounds__(256, 2) void k_attn(const unsigned short* __restrict__ xbf,
                                                 const unsigned short* __restrict__ xT,
                                                 unsigned short* __restrict__ attn) {
  __shared__ float P[4][16 * 68];   // per-wave P transpose (stride 68: 2-way = free)
  __shared__ float CB[4][16 * 64];  // combine chunk buffer
  __shared__ float ML[2][4][16];    // [m|l][wave][row]
  __shared__ float ILF[16];         // 1/l_final per row

  int tid = threadIdx.x;
  int w = tid >> 6, lane = tid & 63;
  int g = lane >> 4, c = lane & 15;

  int bid = blockIdx.x;
  int swz = (bid & 7) * 128 + (bid >> 3);  // bijective XCD swizzle (1024 % 8 == 0)
  int b = swz >> 8;
  int q0 = (swz & 255) * 16;

  const unsigned short* Xb = xbf + b * (S * D);
  const unsigned short* XTb = xT + b * (D * S);

  // Q fragments: lane holds Q[q0+c][dk*32 + 8g .. +8]
  bf16x8 qf[8];
#pragma unroll
  for (int dk = 0; dk < 8; ++dk)
    qf[dk] = *(const bf16x8*)(Xb + (q0 + c) * D + dk * 32 + g * 8);

  const f32x4 zero = {0.f, 0.f, 0.f, 0.f};
  f32x4 acc[16];
#pragma unroll
  for (int i = 0; i < 16; ++i) acc[i] = zero;
  float m_r[4] = {-1e30f, -1e30f, -1e30f, -1e30f};
  float l_r[4] = {0.f, 0.f, 0.f, 0.f};

  float* Pw = P[w];

  for (int j = 0; j < 16; ++j) {
    int kv0 = j * 256 + w * 64;
    // ---- scores: S[q][kv] = sum_d Q[q][d] * K[kv][d]  (4 tiles of 16 kv)
    f32x4 st[4];
#pragma unroll
    for (int t = 0; t < 4; ++t) {
      st[t] = zero;
      const unsigned short* Kr = Xb + (kv0 + t * 16 + c) * D + g * 8;
#pragma unroll
      for (int dk = 0; dk < 8; ++dk) {
        bf16x8 kf = *(const bf16x8*)(Kr + dk * 32);
        st[t] = __builtin_amdgcn_mfma_f32_16x16x32_bf16(qf[dk], kf, st[t], 0, 0, 0);
      }
    }
    // st[t][r] = S_raw[q0+4g+r][kv0+16t+c]

    // ---- online softmax (f32)
    float tm[4];
#pragma unroll
    for (int r = 0; r < 4; ++r)
      tm[r] = fmaxf(fmaxf(st[0][r], st[1][r]), fmaxf(st[2][r], st[3][r]));
#pragma unroll
    for (int off = 1; off < 16; off <<= 1) {
#pragma unroll
      for (int r = 0; r < 4; ++r) tm[r] = fmaxf(tm[r], __shfl_xor(tm[r], off, 64));
    }
    float corr[4];
#pragma unroll
    for (int r = 0; r < 4; ++r) {
      float mn = fmaxf(m_r[r], tm[r]);
      corr[r] = exp2f((m_r[r] - mn) * CSC);
      m_r[r] = mn;
    }
    // ---- exp + row-sum + P-transpose write, fused (no ps[] array)
    float tsum[4] = {0.f, 0.f, 0.f, 0.f};
#pragma unroll
    for (int t = 0; t < 4; ++t) {
#pragma unroll
      for (int r = 0; r < 4; ++r) {
        float p = exp2f((st[t][r] - m_r[r]) * CSC);
        tsum[r] += p;
        Pw[(4 * g + r) * 68 + t * 16 + c] = p;
      }
    }
#pragma unroll
    for (int off = 1; off < 16; off <<= 1) {
#pragma unroll
      for (int r = 0; r < 4; ++r) tsum[r] += __shfl_xor(tsum[r], off, 64);
    }
#pragma unroll
    for (int r = 0; r < 4; ++r) l_r[r] = l_r[r] * corr[r] + tsum[r];
#pragma unroll
    for (int i = 0; i < 16; ++i) {
#pragma unroll
      for (int r = 0; r < 4; ++r) acc[i][r] *= corr[r];
    }

    // ---- PV: O[q][d] += P[q][kv] * V[kv][d]
#pragma unroll
    for (int h = 0; h < 2; ++h) {
      f32x4 p0 = *(const f32x4*)&Pw[c * 68 + h * 32 + g * 8];
      f32x4 p1 = *(const f32x4*)&Pw[c * 68 + h * 32 + g * 8 + 4];
      bf16x8 pa;
#pragma unroll
      for (int jj = 0; jj < 4; ++jj) {
        pa[jj] = (__bf16)p0[jj];
        pa[jj + 4] = (__bf16)p1[jj];
      }
#pragma unroll
      for (int dc = 0; dc < 16; ++dc) {
        bf16x8 vf = *(const bf16x8*)(XTb + (dc * 16 + c) * S + kv0 + h * 32 + g * 8);
        acc[dc] = __builtin_amdgcn_mfma_f32_16x16x32_bf16(pa, vf, acc[dc], 0, 0, 0);
      }
    }
  }

  // ---- epilogue: merge 4 wave partials, divide by l, store bf16
  if (c == 0) {
#pragma unroll
    for (int r = 0; r < 4; ++r) {
      ML[0][w][4 * g + r] = m_r[r];
      ML[1][w][4 * g + r] = l_r[r];
    }
  }
  __syncthreads();

  if (tid < 16) {
    float m0 = ML[0][0][tid], m1 = ML[0][1][tid], m2 = ML[0][2][tid], m3 = ML[0][3][tid];
    float ms = fmaxf(fmaxf(m0, m1), fmaxf(m2, m3));
    float lf = ML[1][0][tid] * exp2f((m0 - ms) * CSC) + ML[1][1][tid] * exp2f((m1 - ms) * CSC) +
               ML[1][2][tid] * exp2f((m2 - ms) * CSC) + ML[1][3][tid] * exp2f((m3 - ms) * CSC);
    ILF[tid] = 1.f / lf;
  }

  float fac[4];
#pragma unroll
  for (int r = 0; r < 4; ++r) {
    int row = 4 * g + r;
    float ms = fmaxf(fmaxf(ML[0][0][row], ML[0][1][row]), fmaxf(ML[0][2][row], ML[0][3][row]));
    fac[r] = exp2f((m_r[r] - ms) * CSC);
  }

  unsigned short* Ab = attn + b * (S * D);
#pragma unroll
  for (int chunk = 0; chunk < 4; ++chunk) {
#pragma unroll
    for (int cc = 0; cc < 4; ++cc) {
      int dc = chunk * 4 + cc;
#pragma unroll
      for (int r = 0; r < 4; ++r) CB[w][(4 * g + r) * 64 + cc * 16 + c] = acc[dc][r] * fac[r];
    }
    __syncthreads();
#pragma unroll
    for (int i = 0; i < 4; ++i) {
      int pos = i * 256 + tid;
      int row = pos >> 6, col = pos & 63;
      float v = CB[0][pos] + CB[1][pos] + CB[2][pos] + CB[3][pos];
      Ab[(q0 + row) * D + chunk * 64 + col] = f2bf(v * ILF[row]);
    }
    __syncthreads();
  }
}

// ---- kernel 4: out[m][o] = scale[o] * sum_d attn[m][d] * Wint[o][d] ----
// grid (1024 m-tiles, 4 o-chunks of 64) -> 4096 waves = 4/SIMD
__global__ __launch_bounds__(64) void k_gemm(const unsigned short* __restrict__ attn,
                                             const unsigned short* __restrict__ wbf,
                                             const float* __restrict__ scale,
                                             float* __restrict__ out) {
  int lane = threadIdx.x, g = lane >> 4, c = lane & 15;
  int m0 = blockIdx.x * 16;
  int o0 = blockIdx.y * 64;
  bf16x8 af[8];
#pragma unroll
  for (int dk = 0; dk < 8; ++dk)
    af[dk] = *(const bf16x8*)(attn + (m0 + c) * D + dk * 32 + g * 8);
  const f32x4 zero = {0.f, 0.f, 0.f, 0.f};
  f32x4 acc[4];
#pragma unroll
  for (int i = 0; i < 4; ++i) acc[i] = zero;
#pragma unroll
  for (int oc = 0; oc < 4; ++oc) {
#pragma unroll
    for (int dk = 0; dk < 8; ++dk) {
      bf16x8 wf = *(const bf16x8*)(wbf + (o0 + oc * 16 + c) * D + dk * 32 + g * 8);
      acc[oc] = __builtin_amdgcn_mfma_f32_16x16x32_bf16(af[dk], wf, acc[oc], 0, 0, 0);
    }
  }
#pragma unroll
  for (int oc = 0; oc < 4; ++oc) {
    float sc = scale[o0 + oc * 16 + c];
#pragma unroll
    for (int r = 0; r < 4; ++r)
      out[(m0 + 4 * g + r) * D + o0 + oc * 16 + c] = acc[oc][r] * sc;
  }
}

extern "C" void kernel_launch(void* const* d_in, const int* in_sizes, int n_in,
                              void* d_out, int out_size, void* d_ws, size_t ws_size,
                              hipStream_t stream) {
  (void)in_sizes; (void)n_in; (void)out_size; (void)ws_size;
  const float* x = (const float*)d_in[0];
  const int* w_int = (const int*)d_in[1];
  const float* scale = (const float*)d_in[2];
  float* out = (float*)d_out;

  char* ws = (char*)d_ws;
  unsigned short* xbf  = (unsigned short*)(ws);
  unsigned short* xT   = (unsigned short*)(ws + 8388608);
  unsigned short* attn = (unsigned short*)(ws + 16777216);
  unsigned short* wbf  = (unsigned short*)(ws + 25165824);

  k_prep<<<dim3(1024), dim3(256), 0, stream>>>(x, xbf, xT);
  k_deqw<<<dim3(256), dim3(256), 0, stream>>>(w_int, wbf);
  k_attn<<<dim3(1024), dim3(256), 0, stream>>>(xbf, xT, attn);
  k_gemm<<<dim3(1024, 4), dim3(64), 0, stream>>>(attn, wbf, scale, out);
}

// Round 4
// 226.199 us; speedup vs baseline: 2.6260x; 2.5678x over previous
//
#include <hip/hip_runtime.h>

typedef __bf16 bf16x8 __attribute__((ext_vector_type(8)));
typedef float f32x4 __attribute__((ext_vector_type(4)));

constexpr int B = 4, S = 4096, D = 256;
// log2(e) / sqrt(D) = 1.4426950408889634 / 16
constexpr float CSC = 0.09016844005556021f;

static __device__ __forceinline__ unsigned short f2bf(float f) {
  unsigned int u = __builtin_bit_cast(unsigned int, f);
  u = (u + 0x7fffu + ((u >> 16) & 1u)) >> 16;
  return (unsigned short)u;
}

// async global->LDS, 16B per lane; LDS dest = wave-uniform base + lane*16
static __device__ __forceinline__ void gld16(const void* g, void* l) {
  __builtin_amdgcn_global_load_lds(
      (const __attribute__((address_space(1))) unsigned int*)g,
      (__attribute__((address_space(3))) unsigned int*)l, 16, 0, 0);
}

// ---- kernel 1: cast x -> bf16, and build xT[b][d][s] (bf16) ----
__global__ __launch_bounds__(256) void k_prep(const float* __restrict__ x,
                                              unsigned short* __restrict__ xbf,
                                              unsigned short* __restrict__ xT) {
  __shared__ unsigned short T[64][65];
  int bid = blockIdx.x;
  int b = bid >> 8, rem = bid & 255;
  int s0 = (rem >> 2) * 64, d0 = (rem & 3) * 64;
  int j = threadIdx.x & 63, i0 = threadIdx.x >> 6;
#pragma unroll
  for (int k = 0; k < 16; ++k) {
    int i = k * 4 + i0;
    int idx = (b * S + s0 + i) * D + d0 + j;
    unsigned short v = f2bf(x[idx]);
    xbf[idx] = v;
    T[j][i] = v;  // T[d_local][s_local]
  }
  __syncthreads();
#pragma unroll
  for (int k = 0; k < 16; ++k) {
    int i = k * 4 + i0;  // d_local row
    xT[(b * D + d0 + i) * S + s0 + j] = T[i][j];
  }
}

// ---- kernel 2: w_int -> bf16 (integers < 256 are exact in bf16) ----
__global__ __launch_bounds__(256) void k_deqw(const int* __restrict__ w,
                                              unsigned short* __restrict__ wbf) {
  int i = blockIdx.x * 256 + threadIdx.x;
  wbf[i] = f2bf((float)w[i]);
}

// ---- kernel 3: flash attention, LDS-staged K/V shared by 4 waves ----
// 256 blocks (1/CU), 4 waves, QBLK=64 (wave w owns q-rows w*16..+15).
// Per KV tile 64: K[64][256] + V^T[256][64] double-buffered in LDS via
// global_load_lds(16B), XOR-swizzle byte^=(row&7)<<4 (source-side + read-side).
__global__ __launch_bounds__(256) void k_attn(const unsigned short* __restrict__ xbf,
                                              const unsigned short* __restrict__ xT,
                                              unsigned short* __restrict__ attn) {
  __shared__ __align__(16) unsigned short Kb[2][64 * 256];   // 32KB x2
  __shared__ __align__(16) unsigned short Vb[2][256 * 64];   // 32KB x2 (V^T: [d][kv])
  __shared__ float P[4][16 * 68];                            // per-wave P transpose

  int tid = threadIdx.x;
  int w = tid >> 6, lane = tid & 63;
  int g = lane >> 4, c = lane & 15;
  int kco = (c & 7) << 4;  // read-side XOR swizzle (bytes)

  int bid = blockIdx.x;
  int swz = (bid & 7) * 32 + (bid >> 3);  // bijective XCD swizzle (256 % 8 == 0)
  int b = swz >> 6;
  int q0 = (swz & 63) * 64;
  int qw0 = q0 + w * 16;

  const unsigned short* Xb = xbf + (size_t)b * (S * D);
  const unsigned short* XTb = xT + (size_t)b * (D * S);

  // Q fragments: lane holds Q[qw0+c][dk*32 + 8g .. +8]
  bf16x8 qf[8];
#pragma unroll
  for (int dk = 0; dk < 8; ++dk)
    qf[dk] = *(const bf16x8*)(Xb + (qw0 + c) * D + dk * 32 + g * 8);

  const f32x4 zero = {0.f, 0.f, 0.f, 0.f};
  f32x4 acc[16];
#pragma unroll
  for (int i = 0; i < 16; ++i) acc[i] = zero;
  float m_r[4] = {-1e30f, -1e30f, -1e30f, -1e30f};
  float l_r[4] = {0.f, 0.f, 0.f, 0.f};

  float* Pw = P[w];

  // stage one KV tile (kv0) into buffer bb; wave w does its own quarter
  auto STAGE = [&](int kv0, int bb) {
#pragma unroll
    for (int i = 0; i < 8; ++i) {  // K rows w*16 .. +15, 2 rows/instr
      int r = w * 16 + i * 2 + (lane >> 5);
      int sc = ((lane & 31) * 16) ^ ((r & 7) << 4);
      gld16((const char*)Xb + (size_t)(kv0 + r) * 512 + sc,
            (char*)Kb[bb] + (w * 16 + i * 2) * 512);
    }
#pragma unroll
    for (int i = 0; i < 8; ++i) {  // V^T d-rows w*64 .. +63, 8 rows/instr
      int dr = w * 64 + i * 8 + (lane >> 3);
      int sc = ((lane & 7) * 16) ^ ((dr & 7) << 4);
      gld16((const char*)XTb + (size_t)dr * 8192 + kv0 * 2 + sc,
            (char*)Vb[bb] + (w * 64 + i * 8) * 128);
    }
  };

  STAGE(0, 0);
  __syncthreads();

  constexpr int NT = S / 64;  // 64 tiles
  for (int it = 0; it < NT; ++it) {
    int bb = it & 1;
    if (it + 1 < NT) STAGE((it + 1) * 64, bb ^ 1);

    // ---- QK^T from Kb[bb]
    f32x4 st[4];
#pragma unroll
    for (int tt = 0; tt < 4; ++tt) {
      st[tt] = zero;
#pragma unroll
      for (int dk = 0; dk < 8; ++dk) {
        bf16x8 kf = *(const bf16x8*)&Kb[bb][(tt * 16 + c) * 256 +
                                            (((dk * 64 + g * 16) ^ kco) >> 1)];
        st[tt] = __builtin_amdgcn_mfma_f32_16x16x32_bf16(qf[dk], kf, st[tt], 0, 0, 0);
      }
    }
    // st[tt][r] = S_raw[qw0+4g+r][it*64+16tt+c]

    // ---- online softmax (f32)
    float tm[4];
#pragma unroll
    for (int r = 0; r < 4; ++r)
      tm[r] = fmaxf(fmaxf(st[0][r], st[1][r]), fmaxf(st[2][r], st[3][r]));
#pragma unroll
    for (int off = 1; off < 16; off <<= 1) {
#pragma unroll
      for (int r = 0; r < 4; ++r) tm[r] = fmaxf(tm[r], __shfl_xor(tm[r], off, 64));
    }
    float corr[4];
#pragma unroll
    for (int r = 0; r < 4; ++r) {
      float mn = fmaxf(m_r[r], tm[r]);
      corr[r] = exp2f((m_r[r] - mn) * CSC);
      m_r[r] = mn;
    }
    float tsum[4] = {0.f, 0.f, 0.f, 0.f};
#pragma unroll
    for (int tt = 0; tt < 4; ++tt) {
#pragma unroll
      for (int r = 0; r < 4; ++r) {
        float p = exp2f((st[tt][r] - m_r[r]) * CSC);
        tsum[r] += p;
        Pw[(4 * g + r) * 68 + tt * 16 + c] = p;
      }
    }
#pragma unroll
    for (int off = 1; off < 16; off <<= 1) {
#pragma unroll
      for (int r = 0; r < 4; ++r) tsum[r] += __shfl_xor(tsum[r], off, 64);
    }
#pragma unroll
    for (int r = 0; r < 4; ++r) l_r[r] = l_r[r] * corr[r] + tsum[r];
#pragma unroll
    for (int i = 0; i < 16; ++i) {
#pragma unroll
      for (int r = 0; r < 4; ++r) acc[i][r] *= corr[r];
    }

    // ---- PV from Vb[bb]
#pragma unroll
    for (int h = 0; h < 2; ++h) {
      f32x4 p0 = *(const f32x4*)&Pw[c * 68 + h * 32 + g * 8];
      f32x4 p1 = *(const f32x4*)&Pw[c * 68 + h * 32 + g * 8 + 4];
      bf16x8 pa;
#pragma unroll
      for (int jj = 0; jj < 4; ++jj) {
        pa[jj] = (__bf16)p0[jj];
        pa[jj + 4] = (__bf16)p1[jj];
      }
#pragma unroll
      for (int dc = 0; dc < 16; ++dc) {
        bf16x8 vf = *(const bf16x8*)&Vb[bb][(dc * 16 + c) * 64 +
                                            (((h * 64 + g * 16) ^ kco) >> 1)];
        acc[dc] = __builtin_amdgcn_mfma_f32_16x16x32_bf16(pa, vf, acc[dc], 0, 0, 0);
      }
    }

    __syncthreads();  // staging of it+1 done; everyone done reading buf bb
  }

  // ---- epilogue: O /= l, store bf16 (wave-private rows, no merge)
  float il[4];
#pragma unroll
  for (int r = 0; r < 4; ++r) il[r] = 1.f / l_r[r];
  unsigned short* Ab = attn + (size_t)b * (S * D);
#pragma unroll
  for (int dc = 0; dc < 16; ++dc) {
#pragma unroll
    for (int r = 0; r < 4; ++r)
      Ab[(qw0 + 4 * g + r) * D + dc * 16 + c] = f2bf(acc[dc][r] * il[r]);
  }
}

// ---- kernel 4: out[m][o] = scale[o] * sum_d attn[m][d] * Wint[o][d] ----
// grid (1024 m-tiles, 4 o-chunks of 64) -> 4096 waves = 4/SIMD
__global__ __launch_bounds__(64) void k_gemm(const unsigned short* __restrict__ attn,
                                             const unsigned short* __restrict__ wbf,
                                             const float* __restrict__ scale,
                                             float* __restrict__ out) {
  int lane = threadIdx.x, g = lane >> 4, c = lane & 15;
  int m0 = blockIdx.x * 16;
  int o0 = blockIdx.y * 64;
  bf16x8 af[8];
#pragma unroll
  for (int dk = 0; dk < 8; ++dk)
    af[dk] = *(const bf16x8*)(attn + (m0 + c) * D + dk * 32 + g * 8);
  const f32x4 zero = {0.f, 0.f, 0.f, 0.f};
  f32x4 acc[4];
#pragma unroll
  for (int i = 0; i < 4; ++i) acc[i] = zero;
#pragma unroll
  for (int oc = 0; oc < 4; ++oc) {
#pragma unroll
    for (int dk = 0; dk < 8; ++dk) {
      bf16x8 wf = *(const bf16x8*)(wbf + (o0 + oc * 16 + c) * D + dk * 32 + g * 8);
      acc[oc] = __builtin_amdgcn_mfma_f32_16x16x32_bf16(af[dk], wf, acc[oc], 0, 0, 0);
    }
  }
#pragma unroll
  for (int oc = 0; oc < 4; ++oc) {
    float sc = scale[o0 + oc * 16 + c];
#pragma unroll
    for (int r = 0; r < 4; ++r)
      out[(m0 + 4 * g + r) * D + o0 + oc * 16 + c] = acc[oc][r] * sc;
  }
}

extern "C" void kernel_launch(void* const* d_in, const int* in_sizes, int n_in,
                              void* d_out, int out_size, void* d_ws, size_t ws_size,
                              hipStream_t stream) {
  (void)in_sizes; (void)n_in; (void)out_size; (void)ws_size;
  const float* x = (const float*)d_in[0];
  const int* w_int = (const int*)d_in[1];
  const float* scale = (const float*)d_in[2];
  float* out = (float*)d_out;

  char* ws = (char*)d_ws;
  unsigned short* xbf  = (unsigned short*)(ws);
  unsigned short* xT   = (unsigned short*)(ws + 8388608);
  unsigned short* attn = (unsigned short*)(ws + 16777216);
  unsigned short* wbf  = (unsigned short*)(ws + 25165824);

  k_prep<<<dim3(1024), dim3(256), 0, stream>>>(x, xbf, xT);
  k_deqw<<<dim3(256), dim3(256), 0, stream>>>(w_int, wbf);
  k_attn<<<dim3(256), dim3(256), 0, stream>>>(xbf, xT, attn);
  k_gemm<<<dim3(1024, 4), dim3(64), 0, stream>>>(attn, wbf, scale, out);
}

// Round 5
// 187.053 us; speedup vs baseline: 3.1756x; 1.2093x over previous
//
#include <hip/hip_runtime.h>

typedef __bf16 bf16x8 __attribute__((ext_vector_type(8)));
typedef float f32x4 __attribute__((ext_vector_type(4)));

constexpr int B = 4, S = 4096, D = 256;
// log2(e) / sqrt(D) = 1.4426950408889634 / 16
constexpr float CSC = 0.09016844005556021f;

static __device__ __forceinline__ unsigned short f2bf(float f) {
  unsigned int u = __builtin_bit_cast(unsigned int, f);
  u = (u + 0x7fffu + ((u >> 16) & 1u)) >> 16;
  return (unsigned short)u;
}

static __device__ __forceinline__ float bf2f(unsigned short u) {
  unsigned int v = ((unsigned int)u) << 16;
  return __builtin_bit_cast(float, v);
}

// pack two f32 -> 2x bf16 (RNE), low half = lo
static __device__ __forceinline__ unsigned int pk2bf(float lo, float hi) {
  unsigned int r;
  asm("v_cvt_pk_bf16_f32 %0, %1, %2" : "=v"(r) : "v"(lo), "v"(hi));
  return r;
}

// async global->LDS, 16B per lane; LDS dest = wave-uniform base + lane*16
static __device__ __forceinline__ void gld16(const void* g, void* l) {
  __builtin_amdgcn_global_load_lds(
      (const __attribute__((address_space(1))) unsigned int*)g,
      (__attribute__((address_space(3))) unsigned int*)l, 16, 0, 0);
}

// ---- kernel 1: cast x -> bf16, and build xT[b][d][s] (bf16) ----
__global__ __launch_bounds__(256) void k_prep(const float* __restrict__ x,
                                              unsigned short* __restrict__ xbf,
                                              unsigned short* __restrict__ xT) {
  __shared__ unsigned short T[64][65];
  int bid = blockIdx.x;
  int b = bid >> 8, rem = bid & 255;
  int s0 = (rem >> 2) * 64, d0 = (rem & 3) * 64;
  int j = threadIdx.x & 63, i0 = threadIdx.x >> 6;
#pragma unroll
  for (int k = 0; k < 16; ++k) {
    int i = k * 4 + i0;
    int idx = (b * S + s0 + i) * D + d0 + j;
    unsigned short v = f2bf(x[idx]);
    xbf[idx] = v;
    T[j][i] = v;  // T[d_local][s_local]
  }
  __syncthreads();
#pragma unroll
  for (int k = 0; k < 16; ++k) {
    int i = k * 4 + i0;  // d_local row
    xT[(b * D + d0 + i) * S + s0 + j] = T[i][j];
  }
}

// ---- kernel 2: w_int -> bf16 (integers < 256 are exact in bf16) ----
__global__ __launch_bounds__(256) void k_deqw(const int* __restrict__ w,
                                              unsigned short* __restrict__ wbf) {
  int i = blockIdx.x * 256 + threadIdx.x;
  wbf[i] = f2bf((float)w[i]);
}

// ---- kernel 3: flash attention, Q=32/wave, split-KV x2 across blocks ----
// 256 blocks = 128 q-groups (128 rows) x 2 kv-halves (2048 kv each).
// 4 waves/block; wave owns 32 q-rows (2 q-sets of 16). KV tile 64,
// double-buffered LDS via global_load_lds(16B) with XOR swizzle (row&7)<<4.
// Swapped QK^T: st = mfma(kf, qf) -> lane(g,c) holds S[kv=16tt+4g+r][q=c],
// so row reductions are 2 shuffle steps. P stored bf16 (cvt_pk). Defer-max
// THR=8 skips acc rescale except at the q.q diagonal spike (~16).
// Outputs UNNORMALIZED partial O (bf16) + (m,l) per row; k_merge combines.
__global__ __launch_bounds__(256, 1) void k_attn(const unsigned short* __restrict__ xbf,
                                                 const unsigned short* __restrict__ xT,
                                                 unsigned short* __restrict__ PO,
                                                 float* __restrict__ ML) {
  __shared__ __align__(16) unsigned short Kb[2][64 * 256];  // 32KB x2
  __shared__ __align__(16) unsigned short Vb[2][256 * 64];  // 32KB x2 (V^T: [d][kv])
  __shared__ __align__(16) unsigned short PW[4][32 * 72];   // per-wave P (bf16), stride 72

  int tid = threadIdx.x;
  int w = tid >> 6, lane = tid & 63;
  int g = lane >> 4, c = lane & 15;
  int kco = (c & 7) << 4;  // read-side XOR swizzle (bytes)

  int bid = blockIdx.x;
  int swz = (bid & 7) * 32 + (bid >> 3);  // bijective XCD swizzle (256 % 8 == 0)
  int h = swz & 1;        // kv half
  int qg = swz >> 1;      // q-group 0..127
  int q0 = qg * 128;      // global q row base
  int bat = q0 >> 12;     // batch
  int qloc = q0 & (S - 1);
  int kvbase = h * 2048;  // in-batch kv start

  const unsigned short* Xb = xbf + (size_t)bat * (S * D);
  const unsigned short* XTb = xT + (size_t)bat * (D * S);

  int qw = qloc + w * 32;  // wave's first q row (in-batch)

  // Q fragments: 2 q-sets of 16 rows
  bf16x8 qf[2][8];
#pragma unroll
  for (int qs = 0; qs < 2; ++qs)
#pragma unroll
    for (int dk = 0; dk < 8; ++dk)
      qf[qs][dk] = *(const bf16x8*)(Xb + (qw + qs * 16 + c) * D + dk * 32 + g * 8);

  const f32x4 zero = {0.f, 0.f, 0.f, 0.f};
  f32x4 acc[2][16];
#pragma unroll
  for (int qs = 0; qs < 2; ++qs)
#pragma unroll
    for (int i = 0; i < 16; ++i) acc[qs][i] = zero;
  float m_r[2] = {-1e30f, -1e30f};
  float l_r[2] = {0.f, 0.f};

  unsigned short* Pw = PW[w];

  // stage one KV tile (kv0 in-batch) into buffer bb; wave w does its quarter
  auto STAGE = [&](int kv0, int bb) {
#pragma unroll
    for (int i = 0; i < 8; ++i) {  // K rows w*16 .. +15, 2 rows/instr
      int r = w * 16 + i * 2 + (lane >> 5);
      int sc = ((lane & 31) * 16) ^ ((r & 7) << 4);
      gld16((const char*)Xb + (size_t)(kv0 + r) * 512 + sc,
            (char*)Kb[bb] + (w * 16 + i * 2) * 512);
    }
#pragma unroll
    for (int i = 0; i < 8; ++i) {  // V^T d-rows w*64 .. +63, 8 rows/instr
      int dr = w * 64 + i * 8 + (lane >> 3);
      int sc = ((lane & 7) * 16) ^ ((dr & 7) << 4);
      gld16((const char*)XTb + (size_t)dr * 8192 + kv0 * 2 + sc,
            (char*)Vb[bb] + (w * 64 + i * 8) * 128);
    }
  };

  STAGE(kvbase, 0);
  __syncthreads();

  constexpr int NT = 2048 / 64;  // 32 tiles per kv half
  for (int it = 0; it < NT; ++it) {
    int bb = it & 1;
    if (it + 1 < NT) STAGE(kvbase + (it + 1) * 64, bb ^ 1);

    // ---- QK^T (swapped): st[qs][tt][r] = S[kv=16tt+4g+r][q=qs*16+c]
    f32x4 st[2][4];
#pragma unroll
    for (int tt = 0; tt < 4; ++tt) {
      st[0][tt] = zero;
      st[1][tt] = zero;
#pragma unroll
      for (int dk = 0; dk < 8; ++dk) {
        bf16x8 kf = *(const bf16x8*)&Kb[bb][(tt * 16 + c) * 256 +
                                            (((dk * 64 + g * 16) ^ kco) >> 1)];
        st[0][tt] = __builtin_amdgcn_mfma_f32_16x16x32_bf16(kf, qf[0][dk], st[0][tt], 0, 0, 0);
        st[1][tt] = __builtin_amdgcn_mfma_f32_16x16x32_bf16(kf, qf[1][dk], st[1][tt], 0, 0, 0);
      }
    }

    // ---- online softmax (row = c domain)
    float tm[2];
#pragma unroll
    for (int qs = 0; qs < 2; ++qs) {
      float t0 = fmaxf(fmaxf(st[qs][0][0], st[qs][0][1]), fmaxf(st[qs][0][2], st[qs][0][3]));
      float t1 = fmaxf(fmaxf(st[qs][1][0], st[qs][1][1]), fmaxf(st[qs][1][2], st[qs][1][3]));
      float t2 = fmaxf(fmaxf(st[qs][2][0], st[qs][2][1]), fmaxf(st[qs][2][2], st[qs][2][3]));
      float t3 = fmaxf(fmaxf(st[qs][3][0], st[qs][3][1]), fmaxf(st[qs][3][2], st[qs][3][3]));
      float t = fmaxf(fmaxf(t0, t1), fmaxf(t2, t3));
      t = fmaxf(t, __shfl_xor(t, 16, 64));
      t = fmaxf(t, __shfl_xor(t, 32, 64));
      tm[qs] = t;
    }
    // defer-max: rescale only when the new tile max exceeds m by THR=8
    bool need = (tm[0] > m_r[0] + 8.f) || (tm[1] > m_r[1] + 8.f);
    if (__any(need)) {
      float mn0 = fmaxf(m_r[0], tm[0]);
      float mn1 = fmaxf(m_r[1], tm[1]);
      float cr0 = exp2f((m_r[0] - mn0) * CSC);
      float cr1 = exp2f((m_r[1] - mn1) * CSC);
      m_r[0] = mn0; m_r[1] = mn1;
      l_r[0] *= cr0; l_r[1] *= cr1;
      // redistribute corr from row=c domain to acc-row (4g+r) domain
#pragma unroll
      for (int r = 0; r < 4; ++r) {
        float ca0 = __shfl(cr0, 4 * g + r, 64);
        float ca1 = __shfl(cr1, 4 * g + r, 64);
#pragma unroll
        for (int dc = 0; dc < 16; ++dc) {
          acc[0][dc][r] *= ca0;
          acc[1][dc][r] *= ca1;
        }
      }
    }

    // ---- P = exp2(st - m), sum, write bf16 to LDS
    float ts[2] = {0.f, 0.f};
#pragma unroll
    for (int qs = 0; qs < 2; ++qs) {
#pragma unroll
      for (int tt = 0; tt < 4; ++tt) {
        float p0 = exp2f((st[qs][tt][0] - m_r[qs]) * CSC);
        float p1 = exp2f((st[qs][tt][1] - m_r[qs]) * CSC);
        float p2 = exp2f((st[qs][tt][2] - m_r[qs]) * CSC);
        float p3 = exp2f((st[qs][tt][3] - m_r[qs]) * CSC);
        ts[qs] += (p0 + p1) + (p2 + p3);
        char* base = (char*)Pw + (qs * 16 + c) * 144 + tt * 32 + g * 8;
        *(unsigned int*)(base) = pk2bf(p0, p1);
        *(unsigned int*)(base + 4) = pk2bf(p2, p3);
      }
      ts[qs] += __shfl_xor(ts[qs], 16, 64);
      ts[qs] += __shfl_xor(ts[qs], 32, 64);
      l_r[qs] += ts[qs];
    }

    // ---- PV: acc[qs][dc] += P[q][kv] * V^T[d][kv]
#pragma unroll
    for (int hh = 0; hh < 2; ++hh) {
      bf16x8 pa0 = *(const bf16x8*)((const char*)Pw + (c)*144 + hh * 64 + g * 16);
      bf16x8 pa1 = *(const bf16x8*)((const char*)Pw + (16 + c) * 144 + hh * 64 + g * 16);
#pragma unroll
      for (int dc = 0; dc < 16; ++dc) {
        bf16x8 vf = *(const bf16x8*)&Vb[bb][(dc * 16 + c) * 64 +
                                            (((hh * 64 + g * 16) ^ kco) >> 1)];
        acc[0][dc] = __builtin_amdgcn_mfma_f32_16x16x32_bf16(pa0, vf, acc[0][dc], 0, 0, 0);
        acc[1][dc] = __builtin_amdgcn_mfma_f32_16x16x32_bf16(pa1, vf, acc[1][dc], 0, 0, 0);
      }
    }

    __syncthreads();  // staging of it+1 done; everyone done reading buf bb
  }

  // ---- epilogue: store UNNORMALIZED partials + (m,l)
  if (g == 0) {
#pragma unroll
    for (int qs = 0; qs < 2; ++qs) {
      int row = q0 + w * 32 + qs * 16 + c;
      ML[((size_t)h * 16384 + row) * 2 + 0] = m_r[qs];
      ML[((size_t)h * 16384 + row) * 2 + 1] = l_r[qs];
    }
  }
  unsigned short* Pb = PO + (size_t)h * 16384 * 256;
#pragma unroll
  for (int qs = 0; qs < 2; ++qs) {
#pragma unroll
    for (int dc = 0; dc < 16; ++dc) {
#pragma unroll
      for (int r = 0; r < 4; ++r) {
        int row = q0 + w * 32 + qs * 16 + 4 * g + r;
        Pb[(size_t)row * 256 + dc * 16 + c] = f2bf(acc[qs][dc][r]);
      }
    }
  }
}

// ---- kernel 3b: merge the two kv-half partials -> attn (bf16) ----
__global__ __launch_bounds__(256) void k_merge(const unsigned short* __restrict__ PO,
                                               const float* __restrict__ ML,
                                               unsigned short* __restrict__ attn) {
  int row = blockIdx.x * 4 + (threadIdx.x >> 6);
  int d4 = (threadIdx.x & 63) * 4;
  float m0 = ML[(size_t)row * 2 + 0], l0 = ML[(size_t)row * 2 + 1];
  float m1 = ML[((size_t)16384 + row) * 2 + 0], l1 = ML[((size_t)16384 + row) * 2 + 1];
  float ms = fmaxf(m0, m1);
  float a0 = exp2f((m0 - ms) * CSC);
  float a1 = exp2f((m1 - ms) * CSC);
  float il = 1.f / (l0 * a0 + l1 * a1);
  const ushort4 u0 = *(const ushort4*)(PO + (size_t)row * 256 + d4);
  const ushort4 u1 = *(const ushort4*)(PO + (size_t)16384 * 256 + (size_t)row * 256 + d4);
  ushort4 o;
  o.x = f2bf((bf2f(u0.x) * a0 + bf2f(u1.x) * a1) * il);
  o.y = f2bf((bf2f(u0.y) * a0 + bf2f(u1.y) * a1) * il);
  o.z = f2bf((bf2f(u0.z) * a0 + bf2f(u1.z) * a1) * il);
  o.w = f2bf((bf2f(u0.w) * a0 + bf2f(u1.w) * a1) * il);
  *(ushort4*)(attn + (size_t)row * 256 + d4) = o;
}

// ---- kernel 4: out[m][o] = scale[o] * sum_d attn[m][d] * Wint[o][d] ----
__global__ __launch_bounds__(64) void k_gemm(const unsigned short* __restrict__ attn,
                                             const unsigned short* __restrict__ wbf,
                                             const float* __restrict__ scale,
                                             float* __restrict__ out) {
  int lane = threadIdx.x, g = lane >> 4, c = lane & 15;
  int m0 = blockIdx.x * 16;
  int o0 = blockIdx.y * 64;
  bf16x8 af[8];
#pragma unroll
  for (int dk = 0; dk < 8; ++dk)
    af[dk] = *(const bf16x8*)(attn + (m0 + c) * D + dk * 32 + g * 8);
  const f32x4 zero = {0.f, 0.f, 0.f, 0.f};
  f32x4 acc[4];
#pragma unroll
  for (int i = 0; i < 4; ++i) acc[i] = zero;
#pragma unroll
  for (int oc = 0; oc < 4; ++oc) {
#pragma unroll
    for (int dk = 0; dk < 8; ++dk) {
      bf16x8 wf = *(const bf16x8*)(wbf + (o0 + oc * 16 + c) * D + dk * 32 + g * 8);
      acc[oc] = __builtin_amdgcn_mfma_f32_16x16x32_bf16(af[dk], wf, acc[oc], 0, 0, 0);
    }
  }
#pragma unroll
  for (int oc = 0; oc < 4; ++oc) {
    float sc = scale[o0 + oc * 16 + c];
#pragma unroll
    for (int r = 0; r < 4; ++r)
      out[(m0 + 4 * g + r) * D + o0 + oc * 16 + c] = acc[oc][r] * sc;
  }
}

extern "C" void kernel_launch(void* const* d_in, const int* in_sizes, int n_in,
                              void* d_out, int out_size, void* d_ws, size_t ws_size,
                              hipStream_t stream) {
  (void)in_sizes; (void)n_in; (void)out_size; (void)ws_size;
  const float* x = (const float*)d_in[0];
  const int* w_int = (const int*)d_in[1];
  const float* scale = (const float*)d_in[2];
  float* out = (float*)d_out;

  char* ws = (char*)d_ws;
  unsigned short* xbf  = (unsigned short*)(ws);              // 8 MB
  unsigned short* xT   = (unsigned short*)(ws + 8388608);    // 8 MB
  unsigned short* attn = (unsigned short*)(ws + 16777216);   // 8 MB
  unsigned short* wbf  = (unsigned short*)(ws + 25165824);   // 128 KB
  unsigned short* PO   = (unsigned short*)(ws + 25296896);   // 16 MB (2x16384x256 bf16)
  float*          ML   = (float*)(ws + 42074112);            // 256 KB (2x16384x2 f32)

  k_prep<<<dim3(1024), dim3(256), 0, stream>>>(x, xbf, xT);
  k_deqw<<<dim3(256), dim3(256), 0, stream>>>(w_int, wbf);
  k_attn<<<dim3(256), dim3(256), 0, stream>>>(xbf, xT, PO, ML);
  k_merge<<<dim3(4096), dim3(256), 0, stream>>>(PO, ML, attn);
  k_gemm<<<dim3(1024, 4), dim3(64), 0, stream>>>(attn, wbf, scale, out);
}